// Round 5
// baseline (460.768 us; speedup 1.0000x reference)
//
#include <hip/hip_runtime.h>

#define NN 50000
#define EE 800000
#define NDIM 128
#define EDIM 32
#define HH 64
#define NBLK 196   // ceil(NN/256)

typedef unsigned short u16;
typedef u16 u16x8 __attribute__((ext_vector_type(8)));
typedef __bf16 bf16x8 __attribute__((ext_vector_type(8)));
typedef float f32x4 __attribute__((ext_vector_type(4)));

// ws layout (bytes)
#define OFF_H32  0ull                        // NN*HH f32 = 12,800,000 (perm aliases this pre-layers)
#define OFF_HBF  12800000ull                 // NN*HH u16 =  6,400,000
#define OFF_NWF  19200000ull                 // 16,384
#define OFF_W1F  (OFF_NWF + 16384ull)        // 49,152
#define OFF_W2F  (OFF_W1F + 49152ull)        // 32,768
#define OFF_FWF  (OFF_W2F + 32768ull)        // 16,384
#define OFF_B1P  (OFF_FWF + 16384ull)        // 1,024
#define OFF_CUR  (OFF_B1P + 1024ull)         // 50176*4 = 200,704
#define OFF_BSUM (OFF_CUR + 200704ull)       // 1,024
#define OFF_SRCP (OFF_BSUM + 1024ull)        // 3,200,000
#define OFF_DSTP (OFF_SRCP + 3200000ull)     // 3,200,000
#define OFF_EAP  (OFF_DSTP + 3200000ull)     // EE*32*2 = 51,200,000
#define WS_NEED  (OFF_EAP + 51200000ull)

__device__ __forceinline__ u16 f2bf(float f) {
  unsigned int u = __builtin_bit_cast(unsigned int, f);
  u += 0x7fffu + ((u >> 16) & 1u);
  return (u16)(u >> 16);
}
__device__ __forceinline__ float bf2f(u16 h) {
  unsigned int u = ((unsigned int)h) << 16;
  return __builtin_bit_cast(float, u);
}

// ---------------------------------------------------------------- setup ----
// Packs weights into MFMA B-fragment order; fuses edge encoder into W1:
// cat = [W1_top ; edge_W @ W1_bot],  b1' = b1 + edge_b @ W1_bot.
// frag(kk,nt,lane,j) = W[kk*32 + (lane>>4)*8 + j][nt*16 + (lane&15)]
__global__ __launch_bounds__(256)
void setup_kernel(const float* __restrict__ node_W, const float* __restrict__ edge_W,
                  const float* __restrict__ edge_b, const float* __restrict__ W1,
                  const float* __restrict__ b1, const float* __restrict__ W2,
                  const float* __restrict__ fin_W1,
                  u16* __restrict__ nWf, u16* __restrict__ W1f, u16* __restrict__ W2f,
                  u16* __restrict__ fWf, float* __restrict__ b1p)
{
  const int tid = threadIdx.x;
  const int blk = blockIdx.x;
  if (blk == 0) {
    for (int idx = tid; idx < 8192; idx += 256) {
      int j = idx & 7, l = (idx >> 3) & 63, nt = (idx >> 9) & 3, kk = idx >> 11;
      int k = kk * 32 + (l >> 4) * 8 + j, n = nt * 16 + (l & 15);
      nWf[idx] = f2bf(node_W[k * HH + n]);
    }
  } else if (blk == 5) {
    for (int idx = tid; idx < 8192; idx += 256) {
      int j = idx & 7, l = (idx >> 3) & 63, nt = (idx >> 9) & 3, kk = idx >> 11;
      int k = kk * 32 + (l >> 4) * 8 + j, n = nt * 16 + (l & 15);
      fWf[idx] = f2bf(fin_W1[k * HH + n]);
    }
  } else {
    const int layer = blk - 1;
    __shared__ float cat[96 * 64];
    const float* W1l = W1 + (size_t)layer * NDIM * HH;
    for (int idx = tid; idx < 4096; idx += 256) cat[idx] = W1l[idx];
    for (int idx = tid; idx < 2048; idx += 256) {
      int a = idx >> 6, n = idx & 63;
      float s = 0.f;
      for (int k = 0; k < 64; ++k) s += edge_W[a * HH + k] * W1l[(64 + k) * HH + n];
      cat[(64 + a) * 64 + n] = s;
    }
    if (tid < 64) {
      float s = b1[layer * HH + tid];
      for (int k = 0; k < 64; ++k) s += edge_b[k] * W1l[(64 + k) * HH + tid];
      b1p[layer * HH + tid] = s;
    }
    __syncthreads();
    for (int idx = tid; idx < 6144; idx += 256) {
      int j = idx & 7, l = (idx >> 3) & 63, nt = (idx >> 9) & 3, kk = idx >> 11;
      int k = kk * 32 + (l >> 4) * 8 + j, n = nt * 16 + (l & 15);
      W1f[layer * 6144 + idx] = f2bf(cat[k * 64 + n]);
    }
    for (int idx = tid; idx < 4096; idx += 256) {
      int j = idx & 7, l = (idx >> 3) & 63, nt = (idx >> 9) & 3, kk = idx >> 11;
      int k = kk * 32 + (l >> 4) * 8 + j, n = nt * 16 + (l & 15);
      W2f[layer * 4096 + idx] = f2bf(W2[((size_t)layer * HH + k) * HH + n]);
    }
  }
}

// ------------------------------------------------------- counting sort -----
__global__ __launch_bounds__(256)
void hist_kernel(const int* __restrict__ ei, int* __restrict__ cnt)
{
  int e = blockIdx.x * 256 + threadIdx.x;
  if (e < EE) atomicAdd(&cnt[ei[EE + e]], 1);
}

__global__ __launch_bounds__(256)
void chunk_sum(const int* __restrict__ cnt, int* __restrict__ bsum)
{
  int i = blockIdx.x * 256 + threadIdx.x;
  int v = (i < NN) ? cnt[i] : 0;
  int lane = threadIdx.x & 63, wv = threadIdx.x >> 6;
#pragma unroll
  for (int m = 1; m < 64; m <<= 1) v += __shfl_xor(v, m, 64);
  __shared__ int ws4[4];
  if (lane == 0) ws4[wv] = v;
  __syncthreads();
  if (threadIdx.x == 0) bsum[blockIdx.x] = ws4[0] + ws4[1] + ws4[2] + ws4[3];
}

__global__ __launch_bounds__(64)
void scan_small(int* __restrict__ bsum)
{
  int lane = threadIdx.x;
  int carry = 0;
  for (int r = 0; r < (NBLK + 63) / 64; ++r) {
    int idx = r * 64 + lane;
    int v = (idx < NBLK) ? bsum[idx] : 0;
    int s = v;
#pragma unroll
    for (int d = 1; d < 64; d <<= 1) {
      int t = __shfl_up(s, d, 64);
      if (lane >= d) s += t;
    }
    if (idx < NBLK) bsum[idx] = s - v + carry;
    carry += __shfl(s, 63, 64);
  }
}

__global__ __launch_bounds__(256)
void scan_write(int* __restrict__ cursor, const int* __restrict__ bsum)
{
  int i = blockIdx.x * 256 + threadIdx.x;
  int v = (i < NN) ? cursor[i] : 0;
  int lane = threadIdx.x & 63, wv = threadIdx.x >> 6;
  int s = v;
#pragma unroll
  for (int d = 1; d < 64; d <<= 1) {
    int t = __shfl_up(s, d, 64);
    if (lane >= d) s += t;
  }
  __shared__ int ws4[4];
  if (lane == 63) ws4[wv] = s;
  __syncthreads();
  int wo = 0;
  for (int w = 0; w < wv; ++w) wo += ws4[w];
  if (i < NN) cursor[i] = s - v + wo + bsum[blockIdx.x];
}

// scatter: only the permutation (4B random writes, L2-merged)
__global__ __launch_bounds__(256)
void scatter_kernel(const int* __restrict__ ei, int* __restrict__ cursor,
                    int* __restrict__ perm)
{
  int e = blockIdx.x * 256 + threadIdx.x;
  if (e >= EE) return;
  int d = ei[EE + e];
  int pos = atomicAdd(&cursor[d], 1);
  perm[pos] = e;
}

// gather_cvt: coalesced writes of srcp/dstp/eap; random 128B reads of edge_attr
__global__ __launch_bounds__(256)
void gather_cvt(const int* __restrict__ perm, const int* __restrict__ ei,
                const float* __restrict__ edge_attr,
                int* __restrict__ srcp, int* __restrict__ dstp, u16* __restrict__ eap)
{
  int t = blockIdx.x * 256 + threadIdx.x;
  int pos = t >> 2, q = t & 3;          // 4 threads per edge
  if (pos >= EE) return;
  int e = perm[pos];
  if (q == 0) srcp[pos] = ei[e];
  if (q == 1) dstp[pos] = ei[EE + e];
  const f32x4* pa = reinterpret_cast<const f32x4*>(edge_attr + (size_t)e * EDIM + q * 8);
  f32x4 v0 = pa[0], v1 = pa[1];
  u16x8 o;
#pragma unroll
  for (int j = 0; j < 4; ++j) { o[j] = f2bf(v0[j]); o[4 + j] = f2bf(v1[j]); }
  *reinterpret_cast<u16x8*>(eap + (size_t)pos * EDIM + q * 8) = o;
}

// ------------------------------------------------------------- node enc ----
#define LDX 136
__global__ __launch_bounds__(256, 4)
void node_enc(const float* __restrict__ x, const u16* __restrict__ nWf,
              const float* __restrict__ node_b, u16* __restrict__ h_bf)
{
  __shared__ u16 Xs[64 * LDX];
  const int tid = threadIdx.x;
  const int base = blockIdx.x * 64;
  const int lane = tid & 63, wv = tid >> 6;
  const int r16 = lane & 15, kg = lane >> 4;

  bf16x8 Bf[4][4];
#pragma unroll
  for (int kk = 0; kk < 4; ++kk)
#pragma unroll
    for (int nt = 0; nt < 4; ++nt)
      Bf[kk][nt] = *reinterpret_cast<const bf16x8*>(nWf + ((kk * 4 + nt) * 64 + lane) * 8);
  float bias[4];
#pragma unroll
  for (int nt = 0; nt < 4; ++nt) bias[nt] = node_b[nt * 16 + r16];

#pragma unroll
  for (int it = 0; it < 4; ++it) {
    int s = it * 256 + tid;
    int r = s >> 4, c = (s & 15) * 8;
    int node = base + r;
    u16x8 o;
    if (node < NN) {
      const f32x4* px = reinterpret_cast<const f32x4*>(x + (size_t)node * NDIM + c);
      f32x4 v0 = px[0], v1 = px[1];
#pragma unroll
      for (int j = 0; j < 4; ++j) { o[j] = f2bf(v0[j]); o[4 + j] = f2bf(v1[j]); }
    } else {
#pragma unroll
      for (int j = 0; j < 8; ++j) o[j] = 0;
    }
    *reinterpret_cast<u16x8*>(&Xs[r * LDX + c]) = o;
  }
  __syncthreads();

  f32x4 acc[4];
#pragma unroll
  for (int nt = 0; nt < 4; ++nt) acc[nt] = (f32x4){0.f, 0.f, 0.f, 0.f};
#pragma unroll
  for (int kk = 0; kk < 4; ++kk) {
    bf16x8 a = *reinterpret_cast<const bf16x8*>(&Xs[(wv * 16 + r16) * LDX + kk * 32 + kg * 8]);
#pragma unroll
    for (int nt = 0; nt < 4; ++nt)
      acc[nt] = __builtin_amdgcn_mfma_f32_16x16x32_bf16(a, Bf[kk][nt], acc[nt], 0, 0, 0);
  }
#pragma unroll
  for (int j = 0; j < 4; ++j) {
    int node = base + wv * 16 + kg * 4 + j;
    if (node < NN) {
#pragma unroll
      for (int nt = 0; nt < 4; ++nt)
        h_bf[(size_t)node * HH + nt * 16 + r16] = f2bf(acc[nt][j] + bias[nt]);
    }
  }
}

// ---------------------------------------------- message (dst-sorted) -------
#define LDI 104   // 96 + 8 pad (u16)
#define LDM 72    // 64 + 8 pad (u16)
#define SMS 66    // f32 stride of message tile
__global__ __launch_bounds__(256, 4)
void msg_sorted(const int* __restrict__ srcp, const int* __restrict__ dstp,
                const u16* __restrict__ eap, const u16* __restrict__ h_bf,
                float* __restrict__ h32, const u16* __restrict__ W1f,
                const u16* __restrict__ W2f, const float* __restrict__ b1p,
                const float* __restrict__ b2a, int layer)
{
  // In (u16, 64xLDI) and Sm (f32, 64xSMS) alias: In dead after GEMM1 reads,
  // Sm written only after the barrier that follows GEMM2.
  __shared__ __align__(16) char bufRaw[64 * SMS * 4];
  u16* In = reinterpret_cast<u16*>(bufRaw);
  float* Sm = reinterpret_cast<float*>(bufRaw);
  __shared__ u16 M1[4][16 * LDM];
  __shared__ int src_s[64], dst_s[64], segpos[64];
  __shared__ int segn;

  const int tid = threadIdx.x;
  const int base = blockIdx.x * 64;
  const int lane = tid & 63, wv = tid >> 6;
  const int r16 = lane & 15, kg = lane >> 4;

  if (tid < 64) src_s[tid] = srcp[base + tid];
  else if (tid < 128) dst_s[tid - 64] = dstp[base + tid - 64];

  bf16x8 B1[3][4], B2[2][4];
  const u16* w1 = W1f + layer * 6144;
  const u16* w2 = W2f + layer * 4096;
#pragma unroll
  for (int kk = 0; kk < 3; ++kk)
#pragma unroll
    for (int nt = 0; nt < 4; ++nt)
      B1[kk][nt] = *reinterpret_cast<const bf16x8*>(w1 + ((kk * 4 + nt) * 64 + lane) * 8);
#pragma unroll
  for (int kk = 0; kk < 2; ++kk)
#pragma unroll
    for (int nt = 0; nt < 4; ++nt)
      B2[kk][nt] = *reinterpret_cast<const bf16x8*>(w2 + ((kk * 4 + nt) * 64 + lane) * 8);
  float b1v[4], b2v[4];
#pragma unroll
  for (int nt = 0; nt < 4; ++nt) {
    b1v[nt] = b1p[layer * HH + nt * 16 + r16];
    b2v[nt] = b2a[layer * HH + nt * 16 + r16];
  }
  __syncthreads();  // indices ready

  // stage h_bf[src]+h_bf[dst] into In[:,0:64]  (dst rows near-uniform -> L1)
#pragma unroll
  for (int it = 0; it < 2; ++it) {
    int s = it * 256 + tid;
    int e = s >> 3, c = (s & 7) * 8;
    u16x8 va = *reinterpret_cast<const u16x8*>(h_bf + (size_t)src_s[e] * HH + c);
    u16x8 vb = *reinterpret_cast<const u16x8*>(h_bf + (size_t)dst_s[e] * HH + c);
    u16x8 o;
#pragma unroll
    for (int j = 0; j < 8; ++j) o[j] = f2bf(bf2f(va[j]) + bf2f(vb[j]));
    *reinterpret_cast<u16x8*>(&In[e * LDI + c]) = o;
  }
  // stage pre-converted bf16 edge_attr into In[:,64:96]
  {
    int e = tid >> 2, c = (tid & 3) * 8;
    u16x8 v = *reinterpret_cast<const u16x8*>(eap + (size_t)(base + e) * EDIM + c);
    *reinterpret_cast<u16x8*>(&In[e * LDI + 64 + c]) = v;
  }
  // wave 0: segment boundaries of the sorted dst tile
  if (wv == 0) {
    bool st = (lane == 0) || (dst_s[lane] != dst_s[lane - 1]);
    unsigned long long m = __ballot(st);
    if (st) {
      int rk = __popcll(m & ((1ull << lane) - 1ull));
      segpos[rk] = lane;
    }
    if (lane == 0) segn = __popcll(m);
  }
  __syncthreads();

  // GEMM1: [64,96] @ [96,64]
  f32x4 acc[4];
#pragma unroll
  for (int nt = 0; nt < 4; ++nt) acc[nt] = (f32x4){0.f, 0.f, 0.f, 0.f};
#pragma unroll
  for (int kk = 0; kk < 3; ++kk) {
    bf16x8 a = *reinterpret_cast<const bf16x8*>(&In[(wv * 16 + r16) * LDI + kk * 32 + kg * 8]);
#pragma unroll
    for (int nt = 0; nt < 4; ++nt)
      acc[nt] = __builtin_amdgcn_mfma_f32_16x16x32_bf16(a, B1[kk][nt], acc[nt], 0, 0, 0);
  }
  // relu+bias -> per-wave M1 (C layout -> A layout); M1 is wave-private
#pragma unroll
  for (int nt = 0; nt < 4; ++nt)
#pragma unroll
    for (int j = 0; j < 4; ++j) {
      float v = fmaxf(acc[nt][j] + b1v[nt], 0.f);
      M1[wv][(kg * 4 + j) * LDM + nt * 16 + r16] = f2bf(v);
    }
  __syncthreads();   // all In reads done; also covers M1 visibility

  // GEMM2: [64,64] @ [64,64]
  f32x4 acc2[4];
#pragma unroll
  for (int nt = 0; nt < 4; ++nt) acc2[nt] = (f32x4){0.f, 0.f, 0.f, 0.f};
#pragma unroll
  for (int kk = 0; kk < 2; ++kk) {
    bf16x8 a = *reinterpret_cast<const bf16x8*>(&M1[wv][r16 * LDM + kk * 32 + kg * 8]);
#pragma unroll
    for (int nt = 0; nt < 4; ++nt)
      acc2[nt] = __builtin_amdgcn_mfma_f32_16x16x32_bf16(a, B2[kk][nt], acc2[nt], 0, 0, 0);
  }
  __syncthreads();   // In fully dead everywhere -> safe to write Sm (alias)

  // message tile (+b2 per edge) to LDS
#pragma unroll
  for (int nt = 0; nt < 4; ++nt)
#pragma unroll
    for (int j = 0; j < 4; ++j)
      Sm[(wv * 16 + kg * 4 + j) * SMS + nt * 16 + r16] = acc2[nt][j] + b2v[nt];
  __syncthreads();

  // segmented reduce: one coalesced 64-lane atomic row per segment
  int ns = segn;
  for (int s = wv; s < ns; s += 4) {
    int r0 = segpos[s];
    int r1 = (s + 1 < ns) ? segpos[s + 1] : 64;
    float sum = 0.f;
    for (int r = r0; r < r1; ++r) sum += Sm[r * SMS + lane];
    unsafeAtomicAdd(&h32[(size_t)dst_s[r0] * HH + lane], sum);
  }
}

// ------------------------------------------ message (fallback, atomic) -----
__global__ __launch_bounds__(256, 2)
void msg_kernel(const int* __restrict__ ei, const float* __restrict__ edge_attr,
                const u16* __restrict__ h_bf, float* __restrict__ h32,
                const u16* __restrict__ W1f, const u16* __restrict__ W2f,
                const float* __restrict__ b1p, const float* __restrict__ b2a,
                int layer)
{
  __shared__ u16 In[64 * LDI];
  __shared__ u16 M1[4][16 * LDM];
  __shared__ int src_s[64], dst_s[64];

  const int tid = threadIdx.x;
  const int base = blockIdx.x * 64;
  const int lane = tid & 63, wv = tid >> 6;
  const int r16 = lane & 15, kg = lane >> 4;

  if (tid < 64) src_s[tid] = ei[base + tid];
  else if (tid < 128) dst_s[tid - 64] = ei[EE + base + tid - 64];

  bf16x8 B1[3][4], B2[2][4];
  const u16* w1 = W1f + layer * 6144;
  const u16* w2 = W2f + layer * 4096;
#pragma unroll
  for (int kk = 0; kk < 3; ++kk)
#pragma unroll
    for (int nt = 0; nt < 4; ++nt)
      B1[kk][nt] = *reinterpret_cast<const bf16x8*>(w1 + ((kk * 4 + nt) * 64 + lane) * 8);
#pragma unroll
  for (int kk = 0; kk < 2; ++kk)
#pragma unroll
    for (int nt = 0; nt < 4; ++nt)
      B2[kk][nt] = *reinterpret_cast<const bf16x8*>(w2 + ((kk * 4 + nt) * 64 + lane) * 8);
  float b1v[4], b2v[4];
#pragma unroll
  for (int nt = 0; nt < 4; ++nt) {
    b1v[nt] = b1p[layer * HH + nt * 16 + r16];
    b2v[nt] = b2a[layer * HH + nt * 16 + r16];
  }
  __syncthreads();

#pragma unroll
  for (int it = 0; it < 2; ++it) {
    int s = it * 256 + tid;
    int e = s >> 3, c = (s & 7) * 8;
    u16x8 va = *reinterpret_cast<const u16x8*>(h_bf + (size_t)src_s[e] * HH + c);
    u16x8 vb = *reinterpret_cast<const u16x8*>(h_bf + (size_t)dst_s[e] * HH + c);
    u16x8 o;
#pragma unroll
    for (int j = 0; j < 8; ++j) o[j] = f2bf(bf2f(va[j]) + bf2f(vb[j]));
    *reinterpret_cast<u16x8*>(&In[e * LDI + c]) = o;
  }
  {
    int e = tid >> 2, c = (tid & 3) * 8;
    const f32x4* pa = reinterpret_cast<const f32x4*>(edge_attr + (size_t)(base + e) * EDIM + c);
    f32x4 v0 = pa[0], v1 = pa[1];
    u16x8 o;
#pragma unroll
    for (int j = 0; j < 4; ++j) { o[j] = f2bf(v0[j]); o[4 + j] = f2bf(v1[j]); }
    *reinterpret_cast<u16x8*>(&In[e * LDI + 64 + c]) = o;
  }
  __syncthreads();

  f32x4 acc[4];
#pragma unroll
  for (int nt = 0; nt < 4; ++nt) acc[nt] = (f32x4){0.f, 0.f, 0.f, 0.f};
#pragma unroll
  for (int kk = 0; kk < 3; ++kk) {
    bf16x8 a = *reinterpret_cast<const bf16x8*>(&In[(wv * 16 + r16) * LDI + kk * 32 + kg * 8]);
#pragma unroll
    for (int nt = 0; nt < 4; ++nt)
      acc[nt] = __builtin_amdgcn_mfma_f32_16x16x32_bf16(a, B1[kk][nt], acc[nt], 0, 0, 0);
  }
#pragma unroll
  for (int nt = 0; nt < 4; ++nt)
#pragma unroll
    for (int j = 0; j < 4; ++j) {
      float v = fmaxf(acc[nt][j] + b1v[nt], 0.f);
      M1[wv][(kg * 4 + j) * LDM + nt * 16 + r16] = f2bf(v);
    }
  __syncthreads();

  f32x4 acc2[4];
#pragma unroll
  for (int nt = 0; nt < 4; ++nt) acc2[nt] = (f32x4){0.f, 0.f, 0.f, 0.f};
#pragma unroll
  for (int kk = 0; kk < 2; ++kk) {
    bf16x8 a = *reinterpret_cast<const bf16x8*>(&M1[wv][r16 * LDM + kk * 32 + kg * 8]);
#pragma unroll
    for (int nt = 0; nt < 4; ++nt)
      acc2[nt] = __builtin_amdgcn_mfma_f32_16x16x32_bf16(a, B2[kk][nt], acc2[nt], 0, 0, 0);
  }
  int dn[4];
#pragma unroll
  for (int j = 0; j < 4; ++j) dn[j] = dst_s[wv * 16 + kg * 4 + j];
#pragma unroll
  for (int j = 0; j < 4; ++j)
#pragma unroll
    for (int nt = 0; nt < 4; ++nt)
      unsafeAtomicAdd(&h32[(size_t)dn[j] * HH + nt * 16 + r16], acc2[nt][j] + b2v[nt]);
}

// ----------------------------------------------- h32->bf16 + re-zero h32 ---
__global__ __launch_bounds__(256)
void cvt_h(float* __restrict__ h32, u16* __restrict__ h_bf)
{
  size_t i = ((size_t)blockIdx.x * 256 + threadIdx.x) * 8;
  if (i >= (size_t)NN * HH) return;
  f32x4* p = reinterpret_cast<f32x4*>(h32 + i);
  f32x4 v0 = p[0], v1 = p[1];
  u16x8 o;
#pragma unroll
  for (int j = 0; j < 4; ++j) { o[j] = f2bf(v0[j]); o[4 + j] = f2bf(v1[j]); }
  *reinterpret_cast<u16x8*>(h_bf + i) = o;
  f32x4 z = (f32x4){0.f, 0.f, 0.f, 0.f};
  p[0] = z;   // zero for next layer: replaces a separate memset dispatch
  p[1] = z;
}

// ---------------------------------------------------------------- final ----
#define LDF 136
__global__ __launch_bounds__(256, 4)
void final_kernel(const int* __restrict__ ei, const u16* __restrict__ h_bf,
                  const u16* __restrict__ fWf, const float* __restrict__ fin_b1,
                  const float* __restrict__ fin_W2, const float* __restrict__ fin_b2,
                  float* __restrict__ out)
{
  __shared__ u16 In[64 * LDF];
  __shared__ int src_s[64], dst_s[64];
  const int tid = threadIdx.x;
  const int base = blockIdx.x * 64;
  const int lane = tid & 63, wv = tid >> 6;
  const int r16 = lane & 15, kg = lane >> 4;

  if (tid < 64) src_s[tid] = ei[base + tid];
  else if (tid < 128) dst_s[tid - 64] = ei[EE + base + tid - 64];

  bf16x8 Bf[4][4];
#pragma unroll
  for (int kk = 0; kk < 4; ++kk)
#pragma unroll
    for (int nt = 0; nt < 4; ++nt)
      Bf[kk][nt] = *reinterpret_cast<const bf16x8*>(fWf + ((kk * 4 + nt) * 64 + lane) * 8);
  float b1v[4], w2v[4];
#pragma unroll
  for (int nt = 0; nt < 4; ++nt) {
    b1v[nt] = fin_b1[nt * 16 + r16];
    w2v[nt] = fin_W2[nt * 16 + r16];
  }
  const float bb = fin_b2[0];
  __syncthreads();

#pragma unroll
  for (int it = 0; it < 4; ++it) {
    int s = it * 256 + tid;
    int e = s >> 4, g = s & 15, c = (g & 7) * 8;
    int nd = (g < 8) ? src_s[e] : dst_s[e];
    u16x8 v = *reinterpret_cast<const u16x8*>(h_bf + (size_t)nd * HH + c);
    *reinterpret_cast<u16x8*>(&In[e * LDF + g * 8]) = v;
  }
  __syncthreads();

  f32x4 acc[4];
#pragma unroll
  for (int nt = 0; nt < 4; ++nt) acc[nt] = (f32x4){0.f, 0.f, 0.f, 0.f};
#pragma unroll
  for (int kk = 0; kk < 4; ++kk) {
    bf16x8 a = *reinterpret_cast<const bf16x8*>(&In[(wv * 16 + r16) * LDF + kk * 32 + kg * 8]);
#pragma unroll
    for (int nt = 0; nt < 4; ++nt)
      acc[nt] = __builtin_amdgcn_mfma_f32_16x16x32_bf16(a, Bf[kk][nt], acc[nt], 0, 0, 0);
  }
  float p[4];
#pragma unroll
  for (int j = 0; j < 4; ++j) {
    float s = 0.f;
#pragma unroll
    for (int nt = 0; nt < 4; ++nt) s += fmaxf(acc[nt][j] + b1v[nt], 0.f) * w2v[nt];
    p[j] = s;
  }
#pragma unroll
  for (int j = 0; j < 4; ++j)
#pragma unroll
    for (int m = 1; m < 16; m <<= 1)
      p[j] += __shfl_xor(p[j], m, 64);
  if (r16 == 0) {
#pragma unroll
    for (int j = 0; j < 4; ++j)
      out[base + wv * 16 + kg * 4 + j] = p[j] + bb;
  }
}

// ---------------------------------------------------------------- launch ---
extern "C" void kernel_launch(void* const* d_in, const int* in_sizes, int n_in,
                              void* d_out, int out_size, void* d_ws, size_t ws_size,
                              hipStream_t stream)
{
  const float* x      = (const float*)d_in[0];
  const float* eattr  = (const float*)d_in[1];
  const int*   ei     = (const int*)d_in[2];
  const float* node_W = (const float*)d_in[3];
  const float* node_b = (const float*)d_in[4];
  const float* edge_W = (const float*)d_in[5];
  const float* edge_b = (const float*)d_in[6];
  const float* W1     = (const float*)d_in[7];
  const float* b1     = (const float*)d_in[8];
  const float* W2     = (const float*)d_in[9];
  const float* b2     = (const float*)d_in[10];
  const float* fin_W1 = (const float*)d_in[11];
  const float* fin_b1 = (const float*)d_in[12];
  const float* fin_W2 = (const float*)d_in[13];
  const float* fin_b2 = (const float*)d_in[14];

  char* ws   = (char*)d_ws;
  float* h32 = (float*)(ws + OFF_H32);
  u16* h_bf  = (u16*)(ws + OFF_HBF);
  u16* nWf   = (u16*)(ws + OFF_NWF);
  u16* W1f   = (u16*)(ws + OFF_W1F);
  u16* W2f   = (u16*)(ws + OFF_W2F);
  u16* fWf   = (u16*)(ws + OFF_FWF);
  float* b1p = (float*)(ws + OFF_B1P);

  setup_kernel<<<6, 256, 0, stream>>>(node_W, edge_W, edge_b, W1, b1, W2, fin_W1,
                                      nWf, W1f, W2f, fWf, b1p);
  node_enc<<<(NN + 63) / 64, 256, 0, stream>>>(x, nWf, node_b, h_bf);

  if (ws_size >= WS_NEED) {
    int* cursor = (int*)(ws + OFF_CUR);
    int* bsum   = (int*)(ws + OFF_BSUM);
    int* srcp   = (int*)(ws + OFF_SRCP);
    int* dstp   = (int*)(ws + OFF_DSTP);
    u16* eap    = (u16*)(ws + OFF_EAP);
    int* perm   = (int*)(ws + OFF_H32);   // aliases h32; dead before first memset

    hipMemsetAsync(cursor, 0, 50176 * sizeof(int), stream);
    hist_kernel<<<(EE + 255) / 256, 256, 0, stream>>>(ei, cursor);
    chunk_sum<<<NBLK, 256, 0, stream>>>(cursor, bsum);
    scan_small<<<1, 64, 0, stream>>>(bsum);
    scan_write<<<NBLK, 256, 0, stream>>>(cursor, bsum);
    scatter_kernel<<<(EE + 255) / 256, 256, 0, stream>>>(ei, cursor, perm);
    gather_cvt<<<(EE * 4 + 255) / 256, 256, 0, stream>>>(perm, ei, eattr, srcp, dstp, eap);

    hipMemsetAsync(h32, 0, (size_t)NN * HH * sizeof(float), stream);  // after perm is dead
    for (int l = 0; l < 4; ++l) {
      msg_sorted<<<EE / 64, 256, 0, stream>>>(srcp, dstp, eap, h_bf, h32, W1f, W2f, b1p, b2, l);
      cvt_h<<<((size_t)NN * HH / 8 + 255) / 256, 256, 0, stream>>>(h32, h_bf);
    }
  } else {
    for (int l = 0; l < 4; ++l) {
      hipMemsetAsync(h32, 0, (size_t)NN * HH * sizeof(float), stream);
      msg_kernel<<<EE / 64, 256, 0, stream>>>(ei, eattr, h_bf, h32, W1f, W2f, b1p, b2, l);
      cvt_h<<<((size_t)NN * HH / 8 + 255) / 256, 256, 0, stream>>>(h32, h_bf);
    }
  }
  final_kernel<<<EE / 64, 256, 0, stream>>>(ei, h_bf, fWf, fin_b1, fin_W2, fin_b2,
                                            (float*)d_out);
}

// Round 7
// 414.326 us; speedup vs baseline: 1.1121x; 1.1121x over previous
//
#include <hip/hip_runtime.h>

#define NN 50000
#define EE 800000
#define NDIM 128
#define EDIM 32
#define HH 64
#define NBLK 196        // ceil(NN/256)
#define NB64 782        // ceil(NN/64)

typedef unsigned short u16;
typedef u16 u16x8 __attribute__((ext_vector_type(8)));
typedef __bf16 bf16x8 __attribute__((ext_vector_type(8)));
typedef float f32x4 __attribute__((ext_vector_type(4)));

// ws layout (bytes) — ~35.8 MB total (ws >= 77 MB proven in rounds 4/5)
#define OFF_H32  0ull                        // NN*HH f32 hsum accumulator
#define OFF_P    12800000ull                 // NN*HH f32 p = h @ W1top
#define OFF_HBF  25600000ull                 // NN*HH u16 final h; perm aliases front 3.2MB
#define OFF_NWF  32000000ull                 // 16,384
#define OFF_W1T  (OFF_NWF + 16384ull)        // 32,768
#define OFF_W1E  (OFF_W1T + 32768ull)        // 16,384
#define OFF_W2F  (OFF_W1E + 16384ull)        // 32,768
#define OFF_FWF  (OFF_W2F + 32768ull)        // 16,384
#define OFF_B1P  (OFF_FWF + 16384ull)        // 1,024
#define OFF_CUR  (OFF_B1P + 1024ull)         // 200,704
#define OFF_DEG  (OFF_CUR + 200704ull)       // 200,704
#define OFF_BSUM (OFF_DEG + 200704ull)       // 1,024
#define OFF_SRCP (OFF_BSUM + 1024ull)        // EE*2 = 1,600,000 (u16)
#define OFF_DSTP (OFF_SRCP + 1600000ull)     // 1,600,000 (u16)
#define WS_NEED  (OFF_DSTP + 1600000ull)

#define LDX 136   // u16 stride (node_enc X tile)
#define LHS 68    // f32 stride (node-level f32 tiles; 68*4 == 136*2 == 272B/row)
#define SMS 66    // f32 stride of message tile
#define LDF 136

__device__ __forceinline__ u16 f2bf(float f) {
  unsigned int u = __builtin_bit_cast(unsigned int, f);
  u += 0x7fffu + ((u >> 16) & 1u);
  return (u16)(u >> 16);
}
__device__ __forceinline__ float bf2f(u16 h) {
  unsigned int u = ((unsigned int)h) << 16;
  return __builtin_bit_cast(float, u);
}
// hi/lo split of 8 f32 -> two bf16x8 fragments (A-side error ~2^-16)
__device__ __forceinline__ void split8(const f32x4 a0, const f32x4 a1,
                                       bf16x8& hi, bf16x8& lo) {
  u16x8 h_, l_;
#pragma unroll
  for (int j = 0; j < 4; ++j) {
    float v = a0[j]; u16 hb = f2bf(v); h_[j] = hb; l_[j] = f2bf(v - bf2f(hb));
    v = a1[j]; hb = f2bf(v); h_[4 + j] = hb; l_[4 + j] = f2bf(v - bf2f(hb));
  }
  hi = __builtin_bit_cast(bf16x8, h_);
  lo = __builtin_bit_cast(bf16x8, l_);
}

// ---------------------------------------------------------------- setup ----
// frag(kk,nt,lane,j) = W[kk*32 + (lane>>4)*8 + j][nt*16 + (lane&15)]
__global__ __launch_bounds__(256)
void setup_kernel(const float* __restrict__ node_W, const float* __restrict__ edge_W,
                  const float* __restrict__ edge_b, const float* __restrict__ W1,
                  const float* __restrict__ b1, const float* __restrict__ W2,
                  const float* __restrict__ fin_W1,
                  u16* __restrict__ nWf, u16* __restrict__ W1T, u16* __restrict__ W1E,
                  u16* __restrict__ W2f, u16* __restrict__ fWf, float* __restrict__ b1p)
{
  const int tid = threadIdx.x;
  const int blk = blockIdx.x;
  if (blk == 0) {
    for (int idx = tid; idx < 8192; idx += 256) {
      int j = idx & 7, l = (idx >> 3) & 63, nt = (idx >> 9) & 3, kk = idx >> 11;
      int k = kk * 32 + (l >> 4) * 8 + j, n = nt * 16 + (l & 15);
      nWf[idx] = f2bf(node_W[k * HH + n]);
    }
  } else if (blk == 5) {
    for (int idx = tid; idx < 8192; idx += 256) {
      int j = idx & 7, l = (idx >> 3) & 63, nt = (idx >> 9) & 3, kk = idx >> 11;
      int k = kk * 32 + (l >> 4) * 8 + j, n = nt * 16 + (l & 15);
      fWf[idx] = f2bf(fin_W1[k * HH + n]);
    }
  } else {
    const int layer = blk - 1;
    __shared__ float e1[32 * 64];
    const float* W1l = W1 + (size_t)layer * NDIM * HH;
    for (int idx = tid; idx < 2048; idx += 256) {
      int a = idx >> 6, n = idx & 63;
      float s = 0.f;
      for (int k = 0; k < 64; ++k) s += edge_W[a * HH + k] * W1l[(64 + k) * HH + n];
      e1[a * 64 + n] = s;
    }
    if (tid < 64) {
      float s = b1[layer * HH + tid];
      for (int k = 0; k < 64; ++k) s += edge_b[k] * W1l[(64 + k) * HH + tid];
      b1p[layer * HH + tid] = s;
    }
    __syncthreads();
    for (int idx = tid; idx < 4096; idx += 256) {  // W1top frags (K=64)
      int j = idx & 7, l = (idx >> 3) & 63, nt = (idx >> 9) & 3, kk = idx >> 11;
      int k = kk * 32 + (l >> 4) * 8 + j, n = nt * 16 + (l & 15);
      W1T[layer * 4096 + idx] = f2bf(W1l[k * HH + n]);
    }
    for (int idx = tid; idx < 2048; idx += 256) {  // W1e' frags (K=32)
      int j = idx & 7, l = (idx >> 3) & 63, nt = idx >> 9;
      int k = (l >> 4) * 8 + j, n = nt * 16 + (l & 15);
      W1E[layer * 2048 + idx] = f2bf(e1[k * 64 + n]);
    }
    for (int idx = tid; idx < 4096; idx += 256) {  // W2 frags (K=64)
      int j = idx & 7, l = (idx >> 3) & 63, nt = (idx >> 9) & 3, kk = idx >> 11;
      int k = kk * 32 + (l >> 4) * 8 + j, n = nt * 16 + (l & 15);
      W2f[layer * 4096 + idx] = f2bf(W2[((size_t)layer * HH + k) * HH + n]);
    }
  }
}

// ------------------------------------------------------- counting sort -----
__global__ __launch_bounds__(256)
void hist_kernel(const int* __restrict__ ei, int* __restrict__ cnt)
{
  int e = blockIdx.x * 256 + threadIdx.x;
  if (e < EE) atomicAdd(&cnt[ei[EE + e]], 1);
}

__global__ __launch_bounds__(256)
void chunk_sum(const int* __restrict__ cnt, int* __restrict__ bsum)
{
  int i = blockIdx.x * 256 + threadIdx.x;
  int v = (i < NN) ? cnt[i] : 0;
  int lane = threadIdx.x & 63, wv = threadIdx.x >> 6;
#pragma unroll
  for (int m = 1; m < 64; m <<= 1) v += __shfl_xor(v, m, 64);
  __shared__ int ws4[4];
  if (lane == 0) ws4[wv] = v;
  __syncthreads();
  if (threadIdx.x == 0) bsum[blockIdx.x] = ws4[0] + ws4[1] + ws4[2] + ws4[3];
}

__global__ __launch_bounds__(64)
void scan_small(int* __restrict__ bsum)
{
  int lane = threadIdx.x;
  int carry = 0;
  for (int r = 0; r < (NBLK + 63) / 64; ++r) {
    int idx = r * 64 + lane;
    int v = (idx < NBLK) ? bsum[idx] : 0;
    int s = v;
#pragma unroll
    for (int d = 1; d < 64; d <<= 1) {
      int t = __shfl_up(s, d, 64);
      if (lane >= d) s += t;
    }
    if (idx < NBLK) bsum[idx] = s - v + carry;
    carry += __shfl(s, 63, 64);
  }
}

__global__ __launch_bounds__(256)
void scan_write(int* __restrict__ cursor, const int* __restrict__ bsum,
                float* __restrict__ degf)
{
  int i = blockIdx.x * 256 + threadIdx.x;
  int v = (i < NN) ? cursor[i] : 0;
  int lane = threadIdx.x & 63, wv = threadIdx.x >> 6;
  int s = v;
#pragma unroll
  for (int d = 1; d < 64; d <<= 1) {
    int t = __shfl_up(s, d, 64);
    if (lane >= d) s += t;
  }
  __shared__ int ws4[4];
  if (lane == 63) ws4[wv] = s;
  __syncthreads();
  int wo = 0;
  for (int w = 0; w < wv; ++w) wo += ws4[w];
  if (i < NN) {
    cursor[i] = s - v + wo + bsum[blockIdx.x];
    degf[i] = (float)v;
  }
}

__global__ __launch_bounds__(256)
void scatter_kernel(const int* __restrict__ ei, int* __restrict__ cursor,
                    int* __restrict__ perm)
{
  int e = blockIdx.x * 256 + threadIdx.x;
  if (e >= EE) return;
  int d = ei[EE + e];
  int pos = atomicAdd(&cursor[d], 1);
  perm[pos] = e;
}

__global__ __launch_bounds__(256)
void gather_idx(const int* __restrict__ perm, const int* __restrict__ ei,
                u16* __restrict__ srcp, u16* __restrict__ dstp)
{
  int pos = blockIdx.x * 256 + threadIdx.x;
  if (pos >= EE) return;
  int e = perm[pos];
  srcp[pos] = (u16)ei[e];
  dstp[pos] = (u16)ei[EE + e];
}

// ------------------------------- node enc: h0 (f32) -> p0 (split GEMM) -----
__global__ __launch_bounds__(256, 2)
void node_enc(const float* __restrict__ x, const u16* __restrict__ nWf,
              const float* __restrict__ node_b, const u16* __restrict__ W1T,
              float* __restrict__ p)
{
  __shared__ __align__(16) char ebuf[64 * 272];   // Xs (u16 LDX) / Hs (f32 LHS) union
  u16* Xs = reinterpret_cast<u16*>(ebuf);
  float* Hs = reinterpret_cast<float*>(ebuf);
  const int tid = threadIdx.x;
  const int base = blockIdx.x * 64;
  const int lane = tid & 63, wv = tid >> 6;
  const int r16 = lane & 15, kg = lane >> 4;

  bf16x8 Bf[4][4];
#pragma unroll
  for (int kk = 0; kk < 4; ++kk)
#pragma unroll
    for (int nt = 0; nt < 4; ++nt)
      Bf[kk][nt] = *reinterpret_cast<const bf16x8*>(nWf + ((kk * 4 + nt) * 64 + lane) * 8);
  float bias[4];
#pragma unroll
  for (int nt = 0; nt < 4; ++nt) bias[nt] = node_b[nt * 16 + r16];

#pragma unroll
  for (int it = 0; it < 4; ++it) {
    int s = it * 256 + tid;
    int r = s >> 4, c = (s & 15) * 8;
    int node = base + r;
    u16x8 o;
    if (node < NN) {
      const f32x4* px = reinterpret_cast<const f32x4*>(x + (size_t)node * NDIM + c);
      f32x4 v0 = px[0], v1 = px[1];
#pragma unroll
      for (int j = 0; j < 4; ++j) { o[j] = f2bf(v0[j]); o[4 + j] = f2bf(v1[j]); }
    } else {
#pragma unroll
      for (int j = 0; j < 8; ++j) o[j] = 0;
    }
    *reinterpret_cast<u16x8*>(&Xs[r * LDX + c]) = o;
  }
  __syncthreads();

  f32x4 acc[4];
#pragma unroll
  for (int nt = 0; nt < 4; ++nt) acc[nt] = (f32x4){0.f, 0.f, 0.f, 0.f};
#pragma unroll
  for (int kk = 0; kk < 4; ++kk) {
    bf16x8 a = *reinterpret_cast<const bf16x8*>(&Xs[(wv * 16 + r16) * LDX + kk * 32 + kg * 8]);
#pragma unroll
    for (int nt = 0; nt < 4; ++nt)
      acc[nt] = __builtin_amdgcn_mfma_f32_16x16x32_bf16(a, Bf[kk][nt], acc[nt], 0, 0, 0);
  }
  __syncthreads();   // all Xs reads done; safe to overwrite with Hs

  // h0 = acc + bias, kept f32 in LDS
#pragma unroll
  for (int nt = 0; nt < 4; ++nt)
#pragma unroll
    for (int j = 0; j < 4; ++j)
      Hs[(wv * 16 + kg * 4 + j) * LHS + nt * 16 + r16] = acc[nt][j] + bias[nt];
  __syncthreads();

  // p0 = h0 @ W1top[0], split-precision A
  bf16x8 Bt[2][4];
#pragma unroll
  for (int kk = 0; kk < 2; ++kk)
#pragma unroll
    for (int nt = 0; nt < 4; ++nt)
      Bt[kk][nt] = *reinterpret_cast<const bf16x8*>(W1T + ((kk * 4 + nt) * 64 + lane) * 8);

  f32x4 acc2[4];
#pragma unroll
  for (int nt = 0; nt < 4; ++nt) acc2[nt] = (f32x4){0.f, 0.f, 0.f, 0.f};
#pragma unroll
  for (int kk = 0; kk < 2; ++kk) {
    const f32x4* pa = reinterpret_cast<const f32x4*>(&Hs[(wv * 16 + r16) * LHS + kk * 32 + kg * 8]);
    f32x4 a0 = pa[0], a1 = pa[1];
    bf16x8 hi, lo;
    split8(a0, a1, hi, lo);
#pragma unroll
    for (int nt = 0; nt < 4; ++nt) {
      acc2[nt] = __builtin_amdgcn_mfma_f32_16x16x32_bf16(hi, Bt[kk][nt], acc2[nt], 0, 0, 0);
      acc2[nt] = __builtin_amdgcn_mfma_f32_16x16x32_bf16(lo, Bt[kk][nt], acc2[nt], 0, 0, 0);
    }
  }
#pragma unroll
  for (int j = 0; j < 4; ++j) {
    int node = base + wv * 16 + kg * 4 + j;
    if (node < NN) {
#pragma unroll
      for (int nt = 0; nt < 4; ++nt)
        p[(size_t)node * HH + nt * 16 + r16] = acc2[nt][j];
    }
  }
}

// --------------------- message: relu(p_src+p_dst+ea@W1e'+b1'), aggregate ---
__global__ __launch_bounds__(256, 4)
void msg2(const int* __restrict__ perm, const u16* __restrict__ srcp,
          const u16* __restrict__ dstp, const float* __restrict__ edge_attr,
          const float* __restrict__ p, float* __restrict__ h32,
          const u16* __restrict__ W1E, const float* __restrict__ b1p, int layer)
{
  __shared__ float Sm[64 * SMS];
  __shared__ u16 src_s[64], dst_s[64];
  __shared__ int perm_s[64], segpos[64];
  __shared__ int segn;

  const int tid = threadIdx.x;
  const int base = blockIdx.x * 64;
  const int lane = tid & 63, wv = tid >> 6;
  const int r16 = lane & 15, kg = lane >> 4;

  if (tid < 64) src_s[tid] = srcp[base + tid];
  else if (tid < 128) dst_s[tid - 64] = dstp[base + tid - 64];
  else if (tid < 192) perm_s[tid - 128] = perm[base + tid - 128];

  bf16x8 B1[4];
  const u16* w1 = W1E + layer * 2048;
#pragma unroll
  for (int nt = 0; nt < 4; ++nt)
    B1[nt] = *reinterpret_cast<const bf16x8*>(w1 + (nt * 64 + lane) * 8);
  float b1v[4];
#pragma unroll
  for (int nt = 0; nt < 4; ++nt) b1v[nt] = b1p[layer * HH + nt * 16 + r16];
  __syncthreads();

  if (wv == 0) {
    bool st = (lane == 0) || (dst_s[lane] != dst_s[lane - 1]);
    unsigned long long m = __ballot(st);
    if (st) {
      int rk = __popcll(m & ((1ull << lane) - 1ull));
      segpos[rk] = lane;
    }
    if (lane == 0) segn = __popcll(m);
  }

  // A-frag: edge_attr row (random 128B row, L3-resident) -> bf16
  int e = perm_s[wv * 16 + r16];
  const f32x4* pe = reinterpret_cast<const f32x4*>(edge_attr + (size_t)e * EDIM + kg * 8);
  f32x4 ev0 = pe[0], ev1 = pe[1];
  u16x8 t;
#pragma unroll
  for (int j = 0; j < 4; ++j) { t[j] = f2bf(ev0[j]); t[4 + j] = f2bf(ev1[j]); }
  bf16x8 af = __builtin_bit_cast(bf16x8, t);

  // C init: p[src]+p[dst]+b1' (exact f32)
  int rs[4], rd[4];
#pragma unroll
  for (int j = 0; j < 4; ++j) {
    int row = wv * 16 + kg * 4 + j;
    rs[j] = src_s[row];
    rd[j] = dst_s[row];
  }
  f32x4 acc[4];
#pragma unroll
  for (int nt = 0; nt < 4; ++nt)
#pragma unroll
    for (int j = 0; j < 4; ++j)
      acc[nt][j] = p[(size_t)rs[j] * HH + nt * 16 + r16]
                 + p[(size_t)rd[j] * HH + nt * 16 + r16] + b1v[nt];

#pragma unroll
  for (int nt = 0; nt < 4; ++nt)
    acc[nt] = __builtin_amdgcn_mfma_f32_16x16x32_bf16(af, B1[nt], acc[nt], 0, 0, 0);

#pragma unroll
  for (int nt = 0; nt < 4; ++nt)
#pragma unroll
    for (int j = 0; j < 4; ++j)
      Sm[(wv * 16 + kg * 4 + j) * SMS + nt * 16 + r16] = fmaxf(acc[nt][j], 0.f);
  __syncthreads();

  int ns = segn;
  for (int s = wv; s < ns; s += 4) {
    int r0 = segpos[s];
    int r1 = (s + 1 < ns) ? segpos[s + 1] : 64;
    float sum = 0.f;
    for (int r = r0; r < r1; ++r) sum += Sm[r * SMS + lane];
    unsafeAtomicAdd(&h32[(size_t)dst_s[r0] * HH + lane], sum);
  }
}

// ------ node update: h = hsum@W2 + deg*b2 (split); p' = h@W1top' (split) ---
__global__ __launch_bounds__(256, 2)
void node_update(float* __restrict__ h32, const float* __restrict__ degf,
                 const u16* __restrict__ W2f, const float* __restrict__ b2a,
                 const u16* __restrict__ W1T, float* __restrict__ p,
                 u16* __restrict__ h_bf, int layer)
{
  __shared__ __align__(16) float Hs[64 * LHS];
  const int tid = threadIdx.x;
  const int base = blockIdx.x * 64;
  const int lane = tid & 63, wv = tid >> 6;
  const int r16 = lane & 15, kg = lane >> 4;

  // stage hsum f32; zero h32 for the next layer
#pragma unroll
  for (int it = 0; it < 2; ++it) {
    int s = it * 256 + tid;
    int r = s >> 3, c = (s & 7) * 8;
    int node = base + r;
    f32x4 v0 = (f32x4){0.f, 0.f, 0.f, 0.f}, v1 = v0;
    if (node < NN) {
      f32x4* ph = reinterpret_cast<f32x4*>(h32 + (size_t)node * HH + c);
      v0 = ph[0]; v1 = ph[1];
      f32x4 z = (f32x4){0.f, 0.f, 0.f, 0.f};
      ph[0] = z; ph[1] = z;
    }
    *reinterpret_cast<f32x4*>(&Hs[r * LHS + c]) = v0;
    *reinterpret_cast<f32x4*>(&Hs[r * LHS + c + 4]) = v1;
  }

  bf16x8 B2[2][4];
  const u16* w2 = W2f + layer * 4096;
#pragma unroll
  for (int kk = 0; kk < 2; ++kk)
#pragma unroll
    for (int nt = 0; nt < 4; ++nt)
      B2[kk][nt] = *reinterpret_cast<const bf16x8*>(w2 + ((kk * 4 + nt) * 64 + lane) * 8);
  float b2v[4];
#pragma unroll
  for (int nt = 0; nt < 4; ++nt) b2v[nt] = b2a[layer * HH + nt * 16 + r16];
  float degj[4];
#pragma unroll
  for (int j = 0; j < 4; ++j) {
    int node = base + wv * 16 + kg * 4 + j;
    degj[j] = (node < NN) ? degf[node] : 0.f;
  }
  __syncthreads();

  // h = hsum @ W2 + deg*b2, split-precision A
  f32x4 acc[4];
#pragma unroll
  for (int nt = 0; nt < 4; ++nt)
#pragma unroll
    for (int j = 0; j < 4; ++j) acc[nt][j] = degj[j] * b2v[nt];
#pragma unroll
  for (int kk = 0; kk < 2; ++kk) {
    const f32x4* pa = reinterpret_cast<const f32x4*>(&Hs[(wv * 16 + r16) * LHS + kk * 32 + kg * 8]);
    f32x4 a0 = pa[0], a1 = pa[1];
    bf16x8 hi, lo;
    split8(a0, a1, hi, lo);
#pragma unroll
    for (int nt = 0; nt < 4; ++nt) {
      acc[nt] = __builtin_amdgcn_mfma_f32_16x16x32_bf16(hi, B2[kk][nt], acc[nt], 0, 0, 0);
      acc[nt] = __builtin_amdgcn_mfma_f32_16x16x32_bf16(lo, B2[kk][nt], acc[nt], 0, 0, 0);
    }
  }

  if (layer == 3) {
#pragma unroll
    for (int j = 0; j < 4; ++j) {
      int node = base + wv * 16 + kg * 4 + j;
      if (node < NN) {
#pragma unroll
        for (int nt = 0; nt < 4; ++nt)
          h_bf[(size_t)node * HH + nt * 16 + r16] = f2bf(acc[nt][j]);
      }
    }
    return;
  }

  // write h (f32) back to Hs, then p' = h @ W1top[layer+1] (split)
  __syncthreads();
#pragma unroll
  for (int nt = 0; nt < 4; ++nt)
#pragma unroll
    for (int j = 0; j < 4; ++j)
      Hs[(wv * 16 + kg * 4 + j) * LHS + nt * 16 + r16] = acc[nt][j];
  __syncthreads();

  bf16x8 Bt[2][4];
  const u16* wt = W1T + (layer + 1) * 4096;
#pragma unroll
  for (int kk = 0; kk < 2; ++kk)
#pragma unroll
    for (int nt = 0; nt < 4; ++nt)
      Bt[kk][nt] = *reinterpret_cast<const bf16x8*>(wt + ((kk * 4 + nt) * 64 + lane) * 8);

  f32x4 acc2[4];
#pragma unroll
  for (int nt = 0; nt < 4; ++nt) acc2[nt] = (f32x4){0.f, 0.f, 0.f, 0.f};
#pragma unroll
  for (int kk = 0; kk < 2; ++kk) {
    const f32x4* pa = reinterpret_cast<const f32x4*>(&Hs[(wv * 16 + r16) * LHS + kk * 32 + kg * 8]);
    f32x4 a0 = pa[0], a1 = pa[1];
    bf16x8 hi, lo;
    split8(a0, a1, hi, lo);
#pragma unroll
    for (int nt = 0; nt < 4; ++nt) {
      acc2[nt] = __builtin_amdgcn_mfma_f32_16x16x32_bf16(hi, Bt[kk][nt], acc2[nt], 0, 0, 0);
      acc2[nt] = __builtin_amdgcn_mfma_f32_16x16x32_bf16(lo, Bt[kk][nt], acc2[nt], 0, 0, 0);
    }
  }
#pragma unroll
  for (int j = 0; j < 4; ++j) {
    int node = base + wv * 16 + kg * 4 + j;
    if (node < NN) {
#pragma unroll
      for (int nt = 0; nt < 4; ++nt)
        p[(size_t)node * HH + nt * 16 + r16] = acc2[nt][j];
    }
  }
}

// ---------------------------------------------------------------- final ----
__global__ __launch_bounds__(256, 2)
void final_kernel(const int* __restrict__ ei, const u16* __restrict__ h_bf,
                  const u16* __restrict__ fWf, const float* __restrict__ fin_b1,
                  const float* __restrict__ fin_W2, const float* __restrict__ fin_b2,
                  float* __restrict__ out)
{
  __shared__ u16 In[64 * LDF];
  __shared__ int src_s[64], dst_s[64];
  const int tid = threadIdx.x;
  const int base = blockIdx.x * 64;
  const int lane = tid & 63, wv = tid >> 6;
  const int r16 = lane & 15, kg = lane >> 4;

  if (tid < 64) src_s[tid] = ei[base + tid];
  else if (tid < 128) dst_s[tid - 64] = ei[EE + base + tid - 64];

  bf16x8 Bf[4][4];
#pragma unroll
  for (int kk = 0; kk < 4; ++kk)
#pragma unroll
    for (int nt = 0; nt < 4; ++nt)
      Bf[kk][nt] = *reinterpret_cast<const bf16x8*>(fWf + ((kk * 4 + nt) * 64 + lane) * 8);
  float b1v[4], w2v[4];
#pragma unroll
  for (int nt = 0; nt < 4; ++nt) {
    b1v[nt] = fin_b1[nt * 16 + r16];
    w2v[nt] = fin_W2[nt * 16 + r16];
  }
  const float bb = fin_b2[0];
  __syncthreads();

#pragma unroll
  for (int it = 0; it < 4; ++it) {
    int s = it * 256 + tid;
    int e = s >> 4, g = s & 15, c = (g & 7) * 8;
    int nd = (g < 8) ? src_s[e] : dst_s[e];
    u16x8 v = *reinterpret_cast<const u16x8*>(h_bf + (size_t)nd * HH + c);
    *reinterpret_cast<u16x8*>(&In[e * LDF + g * 8]) = v;
  }
  __syncthreads();

  f32x4 acc[4];
#pragma unroll
  for (int nt = 0; nt < 4; ++nt) acc[nt] = (f32x4){0.f, 0.f, 0.f, 0.f};
#pragma unroll
  for (int kk = 0; kk < 4; ++kk) {
    bf16x8 a = *reinterpret_cast<const bf16x8*>(&In[(wv * 16 + r16) * LDF + kk * 32 + kg * 8]);
#pragma unroll
    for (int nt = 0; nt < 4; ++nt)
      acc[nt] = __builtin_amdgcn_mfma_f32_16x16x32_bf16(a, Bf[kk][nt], acc[nt], 0, 0, 0);
  }
  float pr[4];
#pragma unroll
  for (int j = 0; j < 4; ++j) {
    float s = 0.f;
#pragma unroll
    for (int nt = 0; nt < 4; ++nt) s += fmaxf(acc[nt][j] + b1v[nt], 0.f) * w2v[nt];
    pr[j] = s;
  }
#pragma unroll
  for (int j = 0; j < 4; ++j)
#pragma unroll
    for (int m = 1; m < 16; m <<= 1)
      pr[j] += __shfl_xor(pr[j], m, 64);
  if (r16 == 0) {
#pragma unroll
    for (int j = 0; j < 4; ++j)
      out[base + wv * 16 + kg * 4 + j] = pr[j] + bb;
  }
}

// ---------------------------------------------------------------- launch ---
extern "C" void kernel_launch(void* const* d_in, const int* in_sizes, int n_in,
                              void* d_out, int out_size, void* d_ws, size_t ws_size,
                              hipStream_t stream)
{
  const float* x      = (const float*)d_in[0];
  const float* eattr  = (const float*)d_in[1];
  const int*   ei     = (const int*)d_in[2];
  const float* node_W = (const float*)d_in[3];
  const float* node_b = (const float*)d_in[4];
  const float* edge_W = (const float*)d_in[5];
  const float* edge_b = (const float*)d_in[6];
  const float* W1     = (const float*)d_in[7];
  const float* b1     = (const float*)d_in[8];
  const float* W2     = (const float*)d_in[9];
  const float* b2     = (const float*)d_in[10];
  const float* fin_W1 = (const float*)d_in[11];
  const float* fin_b1 = (const float*)d_in[12];
  const float* fin_W2 = (const float*)d_in[13];
  const float* fin_b2 = (const float*)d_in[14];

  char* ws    = (char*)d_ws;
  float* h32  = (float*)(ws + OFF_H32);
  float* p    = (float*)(ws + OFF_P);
  u16* h_bf   = (u16*)(ws + OFF_HBF);
  int* perm   = (int*)(ws + OFF_HBF);   // aliases h_bf; perm dead before h_bf written
  u16* nWf    = (u16*)(ws + OFF_NWF);
  u16* W1T    = (u16*)(ws + OFF_W1T);
  u16* W1E    = (u16*)(ws + OFF_W1E);
  u16* W2f    = (u16*)(ws + OFF_W2F);
  u16* fWf    = (u16*)(ws + OFF_FWF);
  float* b1p  = (float*)(ws + OFF_B1P);
  int* cursor = (int*)(ws + OFF_CUR);
  float* degf = (float*)(ws + OFF_DEG);
  int* bsum   = (int*)(ws + OFF_BSUM);
  u16* srcp   = (u16*)(ws + OFF_SRCP);
  u16* dstp   = (u16*)(ws + OFF_DSTP);

  hipMemsetAsync(cursor, 0, 50176 * sizeof(int), stream);
  hipMemsetAsync(h32, 0, (size_t)NN * HH * sizeof(float), stream);

  setup_kernel<<<6, 256, 0, stream>>>(node_W, edge_W, edge_b, W1, b1, W2, fin_W1,
                                      nWf, W1T, W1E, W2f, fWf, b1p);
  node_enc<<<NB64, 256, 0, stream>>>(x, nWf, node_b, W1T, p);

  hist_kernel<<<(EE + 255) / 256, 256, 0, stream>>>(ei, cursor);
  chunk_sum<<<NBLK, 256, 0, stream>>>(cursor, bsum);
  scan_small<<<1, 64, 0, stream>>>(bsum);
  scan_write<<<NBLK, 256, 0, stream>>>(cursor, bsum, degf);
  scatter_kernel<<<(EE + 255) / 256, 256, 0, stream>>>(ei, cursor, perm);
  gather_idx<<<(EE + 255) / 256, 256, 0, stream>>>(perm, ei, srcp, dstp);

  for (int l = 0; l < 4; ++l) {
    msg2<<<EE / 64, 256, 0, stream>>>(perm, srcp, dstp, eattr, p, h32, W1E, b1p, l);
    node_update<<<NB64, 256, 0, stream>>>(h32, degf, W2f, b2, W1T, p, h_bf, l);
  }
  final_kernel<<<EE / 64, 256, 0, stream>>>(ei, h_bf, fWf, fin_b1, fin_W2, fin_b2,
                                            (float*)d_out);
}

// Round 8
// 408.756 us; speedup vs baseline: 1.1272x; 1.0136x over previous
//
#include <hip/hip_runtime.h>

#define NN 50000
#define EE 800000
#define NDIM 128
#define EDIM 32
#define HH 64
#define NBLK 196        // ceil(NN/256)
#define NB64 782        // ceil(NN/64)

typedef unsigned short u16;
typedef u16 u16x8 __attribute__((ext_vector_type(8)));
typedef __bf16 bf16x8 __attribute__((ext_vector_type(8)));
typedef float f32x4 __attribute__((ext_vector_type(4)));

// ws layout (bytes) — ~88.7 MB total (ws = 400 MB per the 0xAA poison fill size)
#define OFF_H32  0ull                        // NN*HH f32 hsum accumulator
#define OFF_P    12800000ull                 // NN*HH f32, PERMUTED: [node][r16*4+nt]
#define OFF_HBF  25600000ull                 // NN*HH u16 final h; perm aliases front 3.2MB
#define OFF_NWF  32000000ull                 // 16,384
#define OFF_W1T  (OFF_NWF + 16384ull)        // 32,768
#define OFF_W1E  (OFF_W1T + 32768ull)        // 16,384
#define OFF_W2F  (OFF_W1E + 16384ull)        // 32,768
#define OFF_FWF  (OFF_W2F + 32768ull)        // 16,384
#define OFF_B1P  (OFF_FWF + 16384ull)        // 1,024
#define OFF_CUR  (OFF_B1P + 1024ull)         // 200,704
#define OFF_DEG  (OFF_CUR + 200704ull)       // 200,704
#define OFF_BSUM (OFF_DEG + 200704ull)       // 1,024
#define OFF_SRCP (OFF_BSUM + 1024ull)        // EE*2 (u16)
#define OFF_DSTP (OFF_SRCP + 1600000ull)     // EE*2 (u16)
#define OFF_EAP  (OFF_DSTP + 1600000ull)     // EE*32*2 = 51,200,000 (bf16, sorted)
#define WS_NEED  (OFF_EAP + 51200000ull)

#define LDX 136   // u16 stride (node_enc X tile)
#define LHS 68    // f32 stride (node-level f32 tiles)
#define SMS 66    // f32 stride of message tile
#define LDF 136

__device__ __forceinline__ u16 f2bf(float f) {
  unsigned int u = __builtin_bit_cast(unsigned int, f);
  u += 0x7fffu + ((u >> 16) & 1u);
  return (u16)(u >> 16);
}
__device__ __forceinline__ float bf2f(u16 h) {
  unsigned int u = ((unsigned int)h) << 16;
  return __builtin_bit_cast(float, u);
}
__device__ __forceinline__ void split8(const f32x4 a0, const f32x4 a1,
                                       bf16x8& hi, bf16x8& lo) {
  u16x8 h_, l_;
#pragma unroll
  for (int j = 0; j < 4; ++j) {
    float v = a0[j]; u16 hb = f2bf(v); h_[j] = hb; l_[j] = f2bf(v - bf2f(hb));
    v = a1[j]; hb = f2bf(v); h_[4 + j] = hb; l_[4 + j] = f2bf(v - bf2f(hb));
  }
  hi = __builtin_bit_cast(bf16x8, h_);
  lo = __builtin_bit_cast(bf16x8, l_);
}

// ---------------------------------------------------------------- setup ----
__global__ __launch_bounds__(256)
void setup_kernel(const float* __restrict__ node_W, const float* __restrict__ edge_W,
                  const float* __restrict__ edge_b, const float* __restrict__ W1,
                  const float* __restrict__ b1, const float* __restrict__ W2,
                  const float* __restrict__ fin_W1,
                  u16* __restrict__ nWf, u16* __restrict__ W1T, u16* __restrict__ W1E,
                  u16* __restrict__ W2f, u16* __restrict__ fWf, float* __restrict__ b1p)
{
  const int tid = threadIdx.x;
  const int blk = blockIdx.x;
  if (blk == 0) {
    for (int idx = tid; idx < 8192; idx += 256) {
      int j = idx & 7, l = (idx >> 3) & 63, nt = (idx >> 9) & 3, kk = idx >> 11;
      int k = kk * 32 + (l >> 4) * 8 + j, n = nt * 16 + (l & 15);
      nWf[idx] = f2bf(node_W[k * HH + n]);
    }
  } else if (blk == 5) {
    for (int idx = tid; idx < 8192; idx += 256) {
      int j = idx & 7, l = (idx >> 3) & 63, nt = (idx >> 9) & 3, kk = idx >> 11;
      int k = kk * 32 + (l >> 4) * 8 + j, n = nt * 16 + (l & 15);
      fWf[idx] = f2bf(fin_W1[k * HH + n]);
    }
  } else {
    const int layer = blk - 1;
    __shared__ float e1[32 * 64];
    const float* W1l = W1 + (size_t)layer * NDIM * HH;
    for (int idx = tid; idx < 2048; idx += 256) {
      int a = idx >> 6, n = idx & 63;
      float s = 0.f;
      for (int k = 0; k < 64; ++k) s += edge_W[a * HH + k] * W1l[(64 + k) * HH + n];
      e1[a * 64 + n] = s;
    }
    if (tid < 64) {
      float s = b1[layer * HH + tid];
      for (int k = 0; k < 64; ++k) s += edge_b[k] * W1l[(64 + k) * HH + tid];
      b1p[layer * HH + tid] = s;
    }
    __syncthreads();
    for (int idx = tid; idx < 4096; idx += 256) {
      int j = idx & 7, l = (idx >> 3) & 63, nt = (idx >> 9) & 3, kk = idx >> 11;
      int k = kk * 32 + (l >> 4) * 8 + j, n = nt * 16 + (l & 15);
      W1T[layer * 4096 + idx] = f2bf(W1l[k * HH + n]);
    }
    for (int idx = tid; idx < 2048; idx += 256) {
      int j = idx & 7, l = (idx >> 3) & 63, nt = idx >> 9;
      int k = (l >> 4) * 8 + j, n = nt * 16 + (l & 15);
      W1E[layer * 2048 + idx] = f2bf(e1[k * 64 + n]);
    }
    for (int idx = tid; idx < 4096; idx += 256) {
      int j = idx & 7, l = (idx >> 3) & 63, nt = (idx >> 9) & 3, kk = idx >> 11;
      int k = kk * 32 + (l >> 4) * 8 + j, n = nt * 16 + (l & 15);
      W2f[layer * 4096 + idx] = f2bf(W2[((size_t)layer * HH + k) * HH + n]);
    }
  }
}

// ------------------------------------------------------- counting sort -----
__global__ __launch_bounds__(256)
void hist_kernel(const int* __restrict__ ei, int* __restrict__ cnt)
{
  int e = blockIdx.x * 256 + threadIdx.x;
  if (e < EE) atomicAdd(&cnt[ei[EE + e]], 1);
}

__global__ __launch_bounds__(256)
void chunk_sum(const int* __restrict__ cnt, int* __restrict__ bsum)
{
  int i = blockIdx.x * 256 + threadIdx.x;
  int v = (i < NN) ? cnt[i] : 0;
  int lane = threadIdx.x & 63, wv = threadIdx.x >> 6;
#pragma unroll
  for (int m = 1; m < 64; m <<= 1) v += __shfl_xor(v, m, 64);
  __shared__ int ws4[4];
  if (lane == 0) ws4[wv] = v;
  __syncthreads();
  if (threadIdx.x == 0) bsum[blockIdx.x] = ws4[0] + ws4[1] + ws4[2] + ws4[3];
}

__global__ __launch_bounds__(64)
void scan_small(int* __restrict__ bsum)
{
  int lane = threadIdx.x;
  int carry = 0;
  for (int r = 0; r < (NBLK + 63) / 64; ++r) {
    int idx = r * 64 + lane;
    int v = (idx < NBLK) ? bsum[idx] : 0;
    int s = v;
#pragma unroll
    for (int d = 1; d < 64; d <<= 1) {
      int t = __shfl_up(s, d, 64);
      if (lane >= d) s += t;
    }
    if (idx < NBLK) bsum[idx] = s - v + carry;
    carry += __shfl(s, 63, 64);
  }
}

__global__ __launch_bounds__(256)
void scan_write(int* __restrict__ cursor, const int* __restrict__ bsum,
                float* __restrict__ degf)
{
  int i = blockIdx.x * 256 + threadIdx.x;
  int v = (i < NN) ? cursor[i] : 0;
  int lane = threadIdx.x & 63, wv = threadIdx.x >> 6;
  int s = v;
#pragma unroll
  for (int d = 1; d < 64; d <<= 1) {
    int t = __shfl_up(s, d, 64);
    if (lane >= d) s += t;
  }
  __shared__ int ws4[4];
  if (lane == 63) ws4[wv] = s;
  __syncthreads();
  int wo = 0;
  for (int w = 0; w < wv; ++w) wo += ws4[w];
  if (i < NN) {
    cursor[i] = s - v + wo + bsum[blockIdx.x];
    degf[i] = (float)v;
  }
}

__global__ __launch_bounds__(256)
void scatter_kernel(const int* __restrict__ ei, int* __restrict__ cursor,
                    int* __restrict__ perm)
{
  int e = blockIdx.x * 256 + threadIdx.x;
  if (e >= EE) return;
  int d = ei[EE + e];
  int pos = atomicAdd(&cursor[d], 1);
  perm[pos] = e;
}

// gather_cvt: build sorted srcp/dstp (u16) + sorted bf16 eap (coalesced writes,
// random L2/L3-resident reads); also zeroes h32 (replaces the slow fillBuffer).
__global__ __launch_bounds__(256)
void gather_cvt(const int* __restrict__ perm, const int* __restrict__ ei,
                const float* __restrict__ edge_attr, u16* __restrict__ srcp,
                u16* __restrict__ dstp, u16* __restrict__ eap,
                float* __restrict__ h32)
{
  int t = blockIdx.x * 256 + threadIdx.x;
  if (t < EE) {  // h32 zero: exactly EE float4 chunks (50000*64/4 == 800000)
    f32x4 z = (f32x4){0.f, 0.f, 0.f, 0.f};
    *reinterpret_cast<f32x4*>(h32 + (size_t)t * 4) = z;
  }
  int pos = t >> 2, q = t & 3;          // 4 threads per edge
  if (pos >= EE) return;
  int e = perm[pos];
  if (q == 0) srcp[pos] = (u16)ei[e];
  if (q == 1) dstp[pos] = (u16)ei[EE + e];
  const f32x4* pa = reinterpret_cast<const f32x4*>(edge_attr + (size_t)e * EDIM + q * 8);
  f32x4 v0 = pa[0], v1 = pa[1];
  u16x8 o;
#pragma unroll
  for (int j = 0; j < 4; ++j) { o[j] = f2bf(v0[j]); o[4 + j] = f2bf(v1[j]); }
  *reinterpret_cast<u16x8*>(eap + (size_t)pos * EDIM + q * 8) = o;
}

// ------------------------------- node enc: h0 (f32) -> p0 (split GEMM) -----
// p storage is PERMUTED: p[node*64 + r16*4 + nt] == logical col nt*16+r16.
__global__ __launch_bounds__(256, 2)
void node_enc(const float* __restrict__ x, const u16* __restrict__ nWf,
              const float* __restrict__ node_b, const u16* __restrict__ W1T,
              float* __restrict__ p)
{
  __shared__ __align__(16) char ebuf[64 * 272];   // Xs (u16 LDX) / Hs (f32 LHS)
  u16* Xs = reinterpret_cast<u16*>(ebuf);
  float* Hs = reinterpret_cast<float*>(ebuf);
  const int tid = threadIdx.x;
  const int base = blockIdx.x * 64;
  const int lane = tid & 63, wv = tid >> 6;
  const int r16 = lane & 15, kg = lane >> 4;

  bf16x8 Bf[4][4];
#pragma unroll
  for (int kk = 0; kk < 4; ++kk)
#pragma unroll
    for (int nt = 0; nt < 4; ++nt)
      Bf[kk][nt] = *reinterpret_cast<const bf16x8*>(nWf + ((kk * 4 + nt) * 64 + lane) * 8);
  float bias[4];
#pragma unroll
  for (int nt = 0; nt < 4; ++nt) bias[nt] = node_b[nt * 16 + r16];

#pragma unroll
  for (int it = 0; it < 4; ++it) {
    int s = it * 256 + tid;
    int r = s >> 4, c = (s & 15) * 8;
    int node = base + r;
    u16x8 o;
    if (node < NN) {
      const f32x4* px = reinterpret_cast<const f32x4*>(x + (size_t)node * NDIM + c);
      f32x4 v0 = px[0], v1 = px[1];
#pragma unroll
      for (int j = 0; j < 4; ++j) { o[j] = f2bf(v0[j]); o[4 + j] = f2bf(v1[j]); }
    } else {
#pragma unroll
      for (int j = 0; j < 8; ++j) o[j] = 0;
    }
    *reinterpret_cast<u16x8*>(&Xs[r * LDX + c]) = o;
  }
  __syncthreads();

  f32x4 acc[4];
#pragma unroll
  for (int nt = 0; nt < 4; ++nt) acc[nt] = (f32x4){0.f, 0.f, 0.f, 0.f};
#pragma unroll
  for (int kk = 0; kk < 4; ++kk) {
    bf16x8 a = *reinterpret_cast<const bf16x8*>(&Xs[(wv * 16 + r16) * LDX + kk * 32 + kg * 8]);
#pragma unroll
    for (int nt = 0; nt < 4; ++nt)
      acc[nt] = __builtin_amdgcn_mfma_f32_16x16x32_bf16(a, Bf[kk][nt], acc[nt], 0, 0, 0);
  }
  __syncthreads();

#pragma unroll
  for (int nt = 0; nt < 4; ++nt)
#pragma unroll
    for (int j = 0; j < 4; ++j)
      Hs[(wv * 16 + kg * 4 + j) * LHS + nt * 16 + r16] = acc[nt][j] + bias[nt];
  __syncthreads();

  bf16x8 Bt[2][4];
#pragma unroll
  for (int kk = 0; kk < 2; ++kk)
#pragma unroll
    for (int nt = 0; nt < 4; ++nt)
      Bt[kk][nt] = *reinterpret_cast<const bf16x8*>(W1T + ((kk * 4 + nt) * 64 + lane) * 8);

  f32x4 acc2[4];
#pragma unroll
  for (int nt = 0; nt < 4; ++nt) acc2[nt] = (f32x4){0.f, 0.f, 0.f, 0.f};
#pragma unroll
  for (int kk = 0; kk < 2; ++kk) {
    const f32x4* pa = reinterpret_cast<const f32x4*>(&Hs[(wv * 16 + r16) * LHS + kk * 32 + kg * 8]);
    f32x4 a0 = pa[0], a1 = pa[1];
    bf16x8 hi, lo;
    split8(a0, a1, hi, lo);
#pragma unroll
    for (int nt = 0; nt < 4; ++nt) {
      acc2[nt] = __builtin_amdgcn_mfma_f32_16x16x32_bf16(hi, Bt[kk][nt], acc2[nt], 0, 0, 0);
      acc2[nt] = __builtin_amdgcn_mfma_f32_16x16x32_bf16(lo, Bt[kk][nt], acc2[nt], 0, 0, 0);
    }
  }
#pragma unroll
  for (int j = 0; j < 4; ++j) {
    int node = base + wv * 16 + kg * 4 + j;
    if (node < NN) {
      f32x4 w;
#pragma unroll
      for (int nt = 0; nt < 4; ++nt) w[nt] = acc2[nt][j];
      *reinterpret_cast<f32x4*>(p + (size_t)node * HH + r16 * 4) = w;
    }
  }
}

// --------------------- message: relu(p_src+p_dst+ea@W1e'+b1'), aggregate ---
__global__ __launch_bounds__(256, 4)
void msg2(const u16* __restrict__ srcp, const u16* __restrict__ dstp,
          const u16* __restrict__ eap, const float* __restrict__ p,
          float* __restrict__ h32, const u16* __restrict__ W1E,
          const float* __restrict__ b1p, int layer)
{
  __shared__ float Sm[64 * SMS];
  __shared__ u16 src_s[64], dst_s[64];
  __shared__ int segpos[64];
  __shared__ int segn;

  const int tid = threadIdx.x;
  const int base = blockIdx.x * 64;
  const int lane = tid & 63, wv = tid >> 6;
  const int r16 = lane & 15, kg = lane >> 4;

  if (tid < 64) src_s[tid] = srcp[base + tid];
  else if (tid < 128) dst_s[tid - 64] = dstp[base + tid - 64];

  bf16x8 B1[4];
  const u16* w1 = W1E + layer * 2048;
#pragma unroll
  for (int nt = 0; nt < 4; ++nt)
    B1[nt] = *reinterpret_cast<const bf16x8*>(w1 + (nt * 64 + lane) * 8);
  float b1v[4];
#pragma unroll
  for (int nt = 0; nt < 4; ++nt) b1v[nt] = b1p[layer * HH + nt * 16 + r16];
  __syncthreads();

  if (wv == 0) {
    bool st = (lane == 0) || (dst_s[lane] != dst_s[lane - 1]);
    unsigned long long m = __ballot(st);
    if (st) {
      int rk = __popcll(m & ((1ull << lane) - 1ull));
      segpos[rk] = lane;
    }
    if (lane == 0) segn = __popcll(m);
  }

  // A-frag: pre-sorted bf16 edge_attr, direct 16B load (streaming)
  bf16x8 af = *reinterpret_cast<const bf16x8*>(
      eap + (size_t)(base + wv * 16 + r16) * EDIM + kg * 8);

  // C init: p[src]+p[dst]+b1' via permuted-layout float4 gathers
  f32x4 acc[4];
#pragma unroll
  for (int j = 0; j < 4; ++j) {
    int row = wv * 16 + kg * 4 + j;
    const f32x4 a = *reinterpret_cast<const f32x4*>(p + (size_t)src_s[row] * HH + r16 * 4);
    const f32x4 b = *reinterpret_cast<const f32x4*>(p + (size_t)dst_s[row] * HH + r16 * 4);
#pragma unroll
    for (int nt = 0; nt < 4; ++nt) acc[nt][j] = a[nt] + b[nt] + b1v[nt];
  }

#pragma unroll
  for (int nt = 0; nt < 4; ++nt)
    acc[nt] = __builtin_amdgcn_mfma_f32_16x16x32_bf16(af, B1[nt], acc[nt], 0, 0, 0);

#pragma unroll
  for (int nt = 0; nt < 4; ++nt)
#pragma unroll
    for (int j = 0; j < 4; ++j)
      Sm[(wv * 16 + kg * 4 + j) * SMS + nt * 16 + r16] = fmaxf(acc[nt][j], 0.f);
  __syncthreads();

  int ns = segn;
  for (int s = wv; s < ns; s += 4) {
    int r0 = segpos[s];
    int r1 = (s + 1 < ns) ? segpos[s + 1] : 64;
    float sum = 0.f;
    for (int r = r0; r < r1; ++r) sum += Sm[r * SMS + lane];
    unsafeAtomicAdd(&h32[(size_t)dst_s[r0] * HH + lane], sum);
  }
}

// ------ node update: h = hsum@W2 + deg*b2 (split); p' = h@W1top' (split) ---
__global__ __launch_bounds__(256, 2)
void node_update(float* __restrict__ h32, const float* __restrict__ degf,
                 const u16* __restrict__ W2f, const float* __restrict__ b2a,
                 const u16* __restrict__ W1T, float* __restrict__ p,
                 u16* __restrict__ h_bf, int layer)
{
  __shared__ __align__(16) float Hs[64 * LHS];
  const int tid = threadIdx.x;
  const int base = blockIdx.x * 64;
  const int lane = tid & 63, wv = tid >> 6;
  const int r16 = lane & 15, kg = lane >> 4;

#pragma unroll
  for (int it = 0; it < 2; ++it) {
    int s = it * 256 + tid;
    int r = s >> 3, c = (s & 7) * 8;
    int node = base + r;
    f32x4 v0 = (f32x4){0.f, 0.f, 0.f, 0.f}, v1 = v0;
    if (node < NN) {
      f32x4* ph = reinterpret_cast<f32x4*>(h32 + (size_t)node * HH + c);
      v0 = ph[0]; v1 = ph[1];
      f32x4 z = (f32x4){0.f, 0.f, 0.f, 0.f};
      ph[0] = z; ph[1] = z;
    }
    *reinterpret_cast<f32x4*>(&Hs[r * LHS + c]) = v0;
    *reinterpret_cast<f32x4*>(&Hs[r * LHS + c + 4]) = v1;
  }

  bf16x8 B2[2][4];
  const u16* w2 = W2f + layer * 4096;
#pragma unroll
  for (int kk = 0; kk < 2; ++kk)
#pragma unroll
    for (int nt = 0; nt < 4; ++nt)
      B2[kk][nt] = *reinterpret_cast<const bf16x8*>(w2 + ((kk * 4 + nt) * 64 + lane) * 8);
  float b2v[4];
#pragma unroll
  for (int nt = 0; nt < 4; ++nt) b2v[nt] = b2a[layer * HH + nt * 16 + r16];
  float degj[4];
#pragma unroll
  for (int j = 0; j < 4; ++j) {
    int node = base + wv * 16 + kg * 4 + j;
    degj[j] = (node < NN) ? degf[node] : 0.f;
  }
  __syncthreads();

  f32x4 acc[4];
#pragma unroll
  for (int nt = 0; nt < 4; ++nt)
#pragma unroll
    for (int j = 0; j < 4; ++j) acc[nt][j] = degj[j] * b2v[nt];
#pragma unroll
  for (int kk = 0; kk < 2; ++kk) {
    const f32x4* pa = reinterpret_cast<const f32x4*>(&Hs[(wv * 16 + r16) * LHS + kk * 32 + kg * 8]);
    f32x4 a0 = pa[0], a1 = pa[1];
    bf16x8 hi, lo;
    split8(a0, a1, hi, lo);
#pragma unroll
    for (int nt = 0; nt < 4; ++nt) {
      acc[nt] = __builtin_amdgcn_mfma_f32_16x16x32_bf16(hi, B2[kk][nt], acc[nt], 0, 0, 0);
      acc[nt] = __builtin_amdgcn_mfma_f32_16x16x32_bf16(lo, B2[kk][nt], acc[nt], 0, 0, 0);
    }
  }

  if (layer == 3) {
#pragma unroll
    for (int j = 0; j < 4; ++j) {
      int node = base + wv * 16 + kg * 4 + j;
      if (node < NN) {
#pragma unroll
        for (int nt = 0; nt < 4; ++nt)
          h_bf[(size_t)node * HH + nt * 16 + r16] = f2bf(acc[nt][j]);
      }
    }
    return;
  }

  __syncthreads();
#pragma unroll
  for (int nt = 0; nt < 4; ++nt)
#pragma unroll
    for (int j = 0; j < 4; ++j)
      Hs[(wv * 16 + kg * 4 + j) * LHS + nt * 16 + r16] = acc[nt][j];
  __syncthreads();

  bf16x8 Bt[2][4];
  const u16* wt = W1T + (layer + 1) * 4096;
#pragma unroll
  for (int kk = 0; kk < 2; ++kk)
#pragma unroll
    for (int nt = 0; nt < 4; ++nt)
      Bt[kk][nt] = *reinterpret_cast<const bf16x8*>(wt + ((kk * 4 + nt) * 64 + lane) * 8);

  f32x4 acc2[4];
#pragma unroll
  for (int nt = 0; nt < 4; ++nt) acc2[nt] = (f32x4){0.f, 0.f, 0.f, 0.f};
#pragma unroll
  for (int kk = 0; kk < 2; ++kk) {
    const f32x4* pa = reinterpret_cast<const f32x4*>(&Hs[(wv * 16 + r16) * LHS + kk * 32 + kg * 8]);
    f32x4 a0 = pa[0], a1 = pa[1];
    bf16x8 hi, lo;
    split8(a0, a1, hi, lo);
#pragma unroll
    for (int nt = 0; nt < 4; ++nt) {
      acc2[nt] = __builtin_amdgcn_mfma_f32_16x16x32_bf16(hi, Bt[kk][nt], acc2[nt], 0, 0, 0);
      acc2[nt] = __builtin_amdgcn_mfma_f32_16x16x32_bf16(lo, Bt[kk][nt], acc2[nt], 0, 0, 0);
    }
  }
#pragma unroll
  for (int j = 0; j < 4; ++j) {
    int node = base + wv * 16 + kg * 4 + j;
    if (node < NN) {
      f32x4 w;
#pragma unroll
      for (int nt = 0; nt < 4; ++nt) w[nt] = acc2[nt][j];
      *reinterpret_cast<f32x4*>(p + (size_t)node * HH + r16 * 4) = w;
    }
  }
}

// ---------------------------------------------------------------- final ----
__global__ __launch_bounds__(256, 2)
void final_kernel(const int* __restrict__ ei, const u16* __restrict__ h_bf,
                  const u16* __restrict__ fWf, const float* __restrict__ fin_b1,
                  const float* __restrict__ fin_W2, const float* __restrict__ fin_b2,
                  float* __restrict__ out)
{
  __shared__ u16 In[64 * LDF];
  __shared__ int src_s[64], dst_s[64];
  const int tid = threadIdx.x;
  const int base = blockIdx.x * 64;
  const int lane = tid & 63, wv = tid >> 6;
  const int r16 = lane & 15, kg = lane >> 4;

  if (tid < 64) src_s[tid] = ei[base + tid];
  else if (tid < 128) dst_s[tid - 64] = ei[EE + base + tid - 64];

  bf16x8 Bf[4][4];
#pragma unroll
  for (int kk = 0; kk < 4; ++kk)
#pragma unroll
    for (int nt = 0; nt < 4; ++nt)
      Bf[kk][nt] = *reinterpret_cast<const bf16x8*>(fWf + ((kk * 4 + nt) * 64 + lane) * 8);
  float b1v[4], w2v[4];
#pragma unroll
  for (int nt = 0; nt < 4; ++nt) {
    b1v[nt] = fin_b1[nt * 16 + r16];
    w2v[nt] = fin_W2[nt * 16 + r16];
  }
  const float bb = fin_b2[0];
  __syncthreads();

#pragma unroll
  for (int it = 0; it < 4; ++it) {
    int s = it * 256 + tid;
    int e = s >> 4, g = s & 15, c = (g & 7) * 8;
    int nd = (g < 8) ? src_s[e] : dst_s[e];
    u16x8 v = *reinterpret_cast<const u16x8*>(h_bf + (size_t)nd * HH + c);
    *reinterpret_cast<u16x8*>(&In[e * LDF + g * 8]) = v;
  }
  __syncthreads();

  f32x4 acc[4];
#pragma unroll
  for (int nt = 0; nt < 4; ++nt) acc[nt] = (f32x4){0.f, 0.f, 0.f, 0.f};
#pragma unroll
  for (int kk = 0; kk < 4; ++kk) {
    bf16x8 a = *reinterpret_cast<const bf16x8*>(&In[(wv * 16 + r16) * LDF + kk * 32 + kg * 8]);
#pragma unroll
    for (int nt = 0; nt < 4; ++nt)
      acc[nt] = __builtin_amdgcn_mfma_f32_16x16x32_bf16(a, Bf[kk][nt], acc[nt], 0, 0, 0);
  }
  float pr[4];
#pragma unroll
  for (int j = 0; j < 4; ++j) {
    float s = 0.f;
#pragma unroll
    for (int nt = 0; nt < 4; ++nt) s += fmaxf(acc[nt][j] + b1v[nt], 0.f) * w2v[nt];
    pr[j] = s;
  }
#pragma unroll
  for (int j = 0; j < 4; ++j)
#pragma unroll
    for (int m = 1; m < 16; m <<= 1)
      pr[j] += __shfl_xor(pr[j], m, 64);
  if (r16 == 0) {
#pragma unroll
    for (int j = 0; j < 4; ++j)
      out[base + wv * 16 + kg * 4 + j] = pr[j] + bb;
  }
}

// ---------------------------------------------------------------- launch ---
extern "C" void kernel_launch(void* const* d_in, const int* in_sizes, int n_in,
                              void* d_out, int out_size, void* d_ws, size_t ws_size,
                              hipStream_t stream)
{
  const float* x      = (const float*)d_in[0];
  const float* eattr  = (const float*)d_in[1];
  const int*   ei     = (const int*)d_in[2];
  const float* node_W = (const float*)d_in[3];
  const float* node_b = (const float*)d_in[4];
  const float* edge_W = (const float*)d_in[5];
  const float* edge_b = (const float*)d_in[6];
  const float* W1     = (const float*)d_in[7];
  const float* b1     = (const float*)d_in[8];
  const float* W2     = (const float*)d_in[9];
  const float* b2     = (const float*)d_in[10];
  const float* fin_W1 = (const float*)d_in[11];
  const float* fin_b1 = (const float*)d_in[12];
  const float* fin_W2 = (const float*)d_in[13];
  const float* fin_b2 = (const float*)d_in[14];

  char* ws    = (char*)d_ws;
  float* h32  = (float*)(ws + OFF_H32);
  float* p    = (float*)(ws + OFF_P);
  u16* h_bf   = (u16*)(ws + OFF_HBF);
  int* perm   = (int*)(ws + OFF_HBF);   // aliases h_bf; perm dead before h_bf written
  u16* nWf    = (u16*)(ws + OFF_NWF);
  u16* W1T    = (u16*)(ws + OFF_W1T);
  u16* W1E    = (u16*)(ws + OFF_W1E);
  u16* W2f    = (u16*)(ws + OFF_W2F);
  u16* fWf    = (u16*)(ws + OFF_FWF);
  float* b1p  = (float*)(ws + OFF_B1P);
  int* cursor = (int*)(ws + OFF_CUR);
  float* degf = (float*)(ws + OFF_DEG);
  int* bsum   = (int*)(ws + OFF_BSUM);
  u16* srcp   = (u16*)(ws + OFF_SRCP);
  u16* dstp   = (u16*)(ws + OFF_DSTP);
  u16* eap    = (u16*)(ws + OFF_EAP);

  hipMemsetAsync(cursor, 0, 50176 * sizeof(int), stream);

  setup_kernel<<<6, 256, 0, stream>>>(node_W, edge_W, edge_b, W1, b1, W2, fin_W1,
                                      nWf, W1T, W1E, W2f, fWf, b1p);
  node_enc<<<NB64, 256, 0, stream>>>(x, nWf, node_b, W1T, p);

  hist_kernel<<<(EE + 255) / 256, 256, 0, stream>>>(ei, cursor);
  chunk_sum<<<NBLK, 256, 0, stream>>>(cursor, bsum);
  scan_small<<<1, 64, 0, stream>>>(bsum);
  scan_write<<<NBLK, 256, 0, stream>>>(cursor, bsum, degf);
  scatter_kernel<<<(EE + 255) / 256, 256, 0, stream>>>(ei, cursor, perm);
  gather_cvt<<<(EE * 4 + 255) / 256, 256, 0, stream>>>(perm, ei, eattr, srcp, dstp,
                                                       eap, h32);

  for (int l = 0; l < 4; ++l) {
    msg2<<<EE / 64, 256, 0, stream>>>(srcp, dstp, eap, p, h32, W1E, b1p, l);
    node_update<<<NB64, 256, 0, stream>>>(h32, degf, W2f, b2, W1T, p, h_bf, l);
  }
  final_kernel<<<EE / 64, 256, 0, stream>>>(ei, h_bf, fWf, fin_b1, fin_W2, fin_b2,
                                            (float*)d_out);
}